// Round 6
// baseline (511.208 us; speedup 1.0000x reference)
//
#include <hip/hip_runtime.h>
#include <hip/hip_bf16.h>
#include <math.h>

#define N_NODES 100000
#define N_EDGES 1600000
#define IN_CH 256
#define HC 128
#define NEG_SLOPE 0.2f

#define NPB 64                                     // nodes per bucket
#define NBUCKETS ((N_NODES + NPB - 1) / NPB)       // 1563
#define BCAP 1536                                  // mean 1024, std 32 -> 16 sigma slack

typedef __attribute__((ext_vector_type(8))) short short8;
typedef __attribute__((ext_vector_type(4))) float floatx4;

__device__ inline ushort f2b(float f) {
    __hip_bfloat16 h = __float2bfloat16(f);
    return *(ushort*)&h;
}

// ---------------------------------------------------------------------------
// Kernel 1: feat_bf16 = bf16(x @ W^T + b), fused attention scores.
// MFMA 16x16x32 bf16. Block = 256 thr (4 waves), BM=128 rows, full N=128.
// ---------------------------------------------------------------------------
#define GBM 128

__global__ __launch_bounds__(256, 2)
void gemm_mfma(const float* __restrict__ x, const float* __restrict__ W,
               const float* __restrict__ b, const float* __restrict__ att,
               __hip_bfloat16* __restrict__ featb,
               float* __restrict__ e_src, float* __restrict__ e_tar,
               float* __restrict__ e_self) {
    __shared__ ushort xs[128][72];
    __shared__ ushort wsh[128][72];

    const int tid  = threadIdx.x;
    const int wave = tid >> 6;
    const int lane = tid & 63;
    const int l16  = lane >> 4;
    const int lc   = lane & 15;
    const int row0 = blockIdx.x * GBM;

    floatx4 acc[2][8];
    #pragma unroll
    for (int mt = 0; mt < 2; ++mt)
        #pragma unroll
        for (int nt = 0; nt < 8; ++nt)
            acc[mt][nt] = (floatx4){0.f, 0.f, 0.f, 0.f};

    for (int kb = 0; kb < 4; ++kb) {           // K chunks of 64
        const int r  = tid >> 4;
        const int kq = tid & 15;
        #pragma unroll
        for (int i = 0; i < 8; ++i) {
            int rr = r + i * 16;
            int gr = row0 + rr;
            float4 v = make_float4(0.f, 0.f, 0.f, 0.f);
            if (gr < N_NODES)
                v = *(const float4*)&x[(size_t)gr * IN_CH + kb * 64 + kq * 4];
            ushort4 u;
            u.x = f2b(v.x); u.y = f2b(v.y); u.z = f2b(v.z); u.w = f2b(v.w);
            *(ushort4*)&xs[rr][kq * 4] = u;
        }
        #pragma unroll
        for (int i = 0; i < 8; ++i) {
            int rr = r + i * 16;
            float4 v = *(const float4*)&W[(size_t)rr * IN_CH + kb * 64 + kq * 4];
            ushort4 u;
            u.x = f2b(v.x); u.y = f2b(v.y); u.z = f2b(v.z); u.w = f2b(v.w);
            *(ushort4*)&wsh[rr][kq * 4] = u;
        }
        __syncthreads();
        #pragma unroll
        for (int ks = 0; ks < 2; ++ks) {
            short8 a0 = *(short8*)&xs[wave * 32 + lc][ks * 32 + l16 * 8];
            short8 a1 = *(short8*)&xs[wave * 32 + 16 + lc][ks * 32 + l16 * 8];
            short8 bf[8];
            #pragma unroll
            for (int nt = 0; nt < 8; ++nt)
                bf[nt] = *(short8*)&wsh[nt * 16 + lc][ks * 32 + l16 * 8];
            #pragma unroll
            for (int nt = 0; nt < 8; ++nt) {
                acc[0][nt] = __builtin_amdgcn_mfma_f32_16x16x32_bf16(a0, bf[nt], acc[0][nt], 0, 0, 0);
                acc[1][nt] = __builtin_amdgcn_mfma_f32_16x16x32_bf16(a1, bf[nt], acc[1][nt], 0, 0, 0);
            }
        }
        __syncthreads();
    }

    float av0[8], av1[8], bc[8];
    #pragma unroll
    for (int nt = 0; nt < 8; ++nt) {
        float2 av = *(const float2*)&att[(nt * 16 + lc) * 2];
        av0[nt] = av.x; av1[nt] = av.y;
        bc[nt] = b[nt * 16 + lc];
    }

    #pragma unroll
    for (int mt = 0; mt < 2; ++mt) {
        #pragma unroll
        for (int rg = 0; rg < 4; ++rg) {
            int row = row0 + wave * 32 + mt * 16 + l16 * 4 + rg;
            float s = 0.f, t = 0.f;
            float vals[8];
            #pragma unroll
            for (int nt = 0; nt < 8; ++nt) {
                float v = acc[mt][nt][rg] + bc[nt];
                vals[nt] = v;
                s += v * av0[nt];
                t += v * av1[nt];
            }
            #pragma unroll
            for (int off = 8; off; off >>= 1) {
                s += __shfl_xor(s, off);
                t += __shfl_xor(t, off);
            }
            if (row < N_NODES) {
                if (lc == 0) {
                    e_src[row] = s;
                    e_tar[row] = t;
                    float z = s + t;
                    float lr = z > 0.f ? z : NEG_SLOPE * z;
                    e_self[row] = __expf(lr);
                }
                #pragma unroll
                for (int nt = 0; nt < 8; ++nt)
                    featb[(size_t)row * HC + nt * 16 + lc] = __float2bfloat16(vals[nt]);
            }
        }
    }
}

// ---------------------------------------------------------------------------
// Binned CSR build.
// bin_k: edges -> per-bucket append (packed: src | local_tar<<17), 4B writes
//        at 1563 sequential write heads (good line locality).
// ---------------------------------------------------------------------------
__global__ __launch_bounds__(256)
void bin_k(const int* __restrict__ ei, int* __restrict__ bcnt,
           int* __restrict__ bstore) {
    int k = blockIdx.x * 256 + threadIdx.x;
    if (k >= N_EDGES) return;
    int t = ei[k];
    int s = ei[N_EDGES + k];
    int bk = t >> 6;                       // t / NPB
    int pos = atomicAdd(&bcnt[bk], 1);
    if (pos < BCAP)
        bstore[bk * BCAP + pos] = s | ((t & (NPB - 1)) << 17);
}

// single-block exclusive scan over NBUCKETS counts
__global__ __launch_bounds__(256)
void bucket_scan_k(const int* __restrict__ bcnt, int* __restrict__ bbase) {
    __shared__ int sdata[256];
    const int PER = (NBUCKETS + 255) / 256;   // 7
    int t = threadIdx.x;
    int ex[PER];
    int run = 0;
    #pragma unroll
    for (int i = 0; i < PER; ++i) {
        int idx = t * PER + i;
        int c = (idx < NBUCKETS) ? bcnt[idx] : 0;
        ex[i] = run;
        run += c;
    }
    sdata[t] = run;
    __syncthreads();
    for (int off = 1; off < 256; off <<= 1) {
        int xx = (t >= off) ? sdata[t - off] : 0;
        __syncthreads();
        sdata[t] += xx;
        __syncthreads();
    }
    int excl = sdata[t] - run;
    #pragma unroll
    for (int i = 0; i < PER; ++i) {
        int idx = t * PER + i;
        if (idx < NBUCKETS) bbase[idx] = excl + ex[i];
    }
}

// one block per bucket: LDS histogram -> prefix -> LDS scatter -> coalesced out
__global__ __launch_bounds__(256)
void bucket_csr_k(const int* __restrict__ bcnt, const int* __restrict__ bbase,
                  const int* __restrict__ bstore, int* __restrict__ offsets,
                  int* __restrict__ csr_src) {
    int b = blockIdx.x;
    int count = bcnt[b]; if (count > BCAP) count = BCAP;
    int base = bbase[b];
    __shared__ int lcnt[NPB];
    __shared__ int lofs[NPB + 1];
    __shared__ int lout[BCAP];

    for (int i = threadIdx.x; i < NPB; i += 256) lcnt[i] = 0;
    __syncthreads();

    const int* st = &bstore[b * BCAP];
    for (int i = threadIdx.x; i < count; i += 256)
        atomicAdd(&lcnt[(st[i] >> 17) & (NPB - 1)], 1);
    __syncthreads();

    if (threadIdx.x == 0) {
        int run = 0;
        #pragma unroll 8
        for (int i = 0; i < NPB; ++i) { lofs[i] = run; run += lcnt[i]; }
        lofs[NPB] = run;
    }
    __syncthreads();

    for (int i = threadIdx.x; i < NPB; i += 256) lcnt[i] = lofs[i];  // reuse as cursor
    __syncthreads();

    for (int i = threadIdx.x; i < count; i += 256) {
        int v = st[i];
        int tl = (v >> 17) & (NPB - 1);
        int pos = atomicAdd(&lcnt[tl], 1);
        lout[pos] = v & 0x1FFFF;
    }
    __syncthreads();

    for (int i = threadIdx.x; i < count; i += 256)
        csr_src[base + i] = lout[i];

    int node0 = b * NPB;
    for (int i = threadIdx.x; i < NPB; i += 256) {
        int n = node0 + i;
        if (n < N_NODES) offsets[n] = base + lofs[i];
    }
    if (b == NBUCKETS - 1 && threadIdx.x == 0)
        offsets[N_NODES] = base + count;
}

// ---------------------------------------------------------------------------
// Aggregate: one wave per node, SINGLE pass, unnormalized accumulate.
// ---------------------------------------------------------------------------
__device__ inline float edge_e(float z) {
    float lr = z > 0.f ? z : NEG_SLOPE * z;
    return __expf(lr);
}

__global__ __launch_bounds__(256)
void aggregate_k(const int* __restrict__ offsets, const int* __restrict__ csr_src,
                 const float* __restrict__ e_src, const float* __restrict__ e_tar,
                 const __hip_bfloat162* __restrict__ featb,
                 const float* __restrict__ e_self, float* __restrict__ out) {
    int node = blockIdx.x * 4 + (threadIdx.x >> 6);
    if (node >= N_NODES) return;
    int lane = threadIdx.x & 63;
    int beg = offsets[node];
    int end = offsets[node + 1];
    float et = e_tar[node];
    float eself = e_self[node];

    float2 fs = __bfloat1622float2(featb[(size_t)node * 64 + lane]);
    float esum = eself;
    float accx = eself * fs.x, accy = eself * fs.y;

    int j = beg;
    for (; j + 3 < end; j += 4) {
        int s0 = csr_src[j];
        int s1 = csr_src[j + 1];
        int s2 = csr_src[j + 2];
        int s3 = csr_src[j + 3];
        float e0 = edge_e(e_src[s0] + et);
        float e1 = edge_e(e_src[s1] + et);
        float e2 = edge_e(e_src[s2] + et);
        float e3 = edge_e(e_src[s3] + et);
        float2 f0 = __bfloat1622float2(featb[(size_t)s0 * 64 + lane]);
        float2 f1 = __bfloat1622float2(featb[(size_t)s1 * 64 + lane]);
        float2 f2 = __bfloat1622float2(featb[(size_t)s2 * 64 + lane]);
        float2 f3 = __bfloat1622float2(featb[(size_t)s3 * 64 + lane]);
        esum += (e0 + e1) + (e2 + e3);
        accx += e0 * f0.x + e1 * f1.x + e2 * f2.x + e3 * f3.x;
        accy += e0 * f0.y + e1 * f1.y + e2 * f2.y + e3 * f3.y;
    }
    for (; j < end; ++j) {
        int s0 = csr_src[j];
        float e0 = edge_e(e_src[s0] + et);
        float2 f0 = __bfloat1622float2(featb[(size_t)s0 * 64 + lane]);
        esum += e0;
        accx += e0 * f0.x;
        accy += e0 * f0.y;
    }
    float inv = 1.f / esum;
    *(float2*)&out[(size_t)node * HC + lane * 2] = make_float2(accx * inv, accy * inv);
}

// ---------------------------------------------------------------------------
extern "C" void kernel_launch(void* const* d_in, const int* in_sizes, int n_in,
                              void* d_out, int out_size, void* d_ws, size_t ws_size,
                              hipStream_t stream) {
    const float* x   = (const float*)d_in[0];
    const int*   ei  = (const int*)d_in[1];     // [0:NE)=tar, [NE:2NE)=src
    const float* W   = (const float*)d_in[2];
    const float* b   = (const float*)d_in[3];
    const float* att = (const float*)d_in[4];
    float* out = (float*)d_out;

    __hip_bfloat16* featb = (__hip_bfloat16*)d_ws;            // N*128 bf16 = 25.6 MB
    float* e_src   = (float*)(featb + (size_t)N_NODES * HC);
    float* e_tar   = e_src   + N_NODES;
    float* e_self  = e_tar   + N_NODES;
    int*   offsets = (int*)(e_self + N_NODES);                 // N+1
    int*   bcnt    = offsets + N_NODES + 1;                    // NBUCKETS
    int*   bbase   = bcnt    + NBUCKETS;                       // NBUCKETS
    int*   csr_src = bbase   + NBUCKETS;                       // N_EDGES
    int*   bstore  = csr_src + N_EDGES;                        // NBUCKETS*BCAP (9.6 MB)

    (void)hipMemsetAsync(bcnt, 0, NBUCKETS * sizeof(int), stream);

    // Binned CSR topology build
    bin_k<<<(N_EDGES + 255) / 256, 256, 0, stream>>>(ei, bcnt, bstore);
    bucket_scan_k<<<1, 256, 0, stream>>>(bcnt, bbase);
    bucket_csr_k<<<NBUCKETS, 256, 0, stream>>>(bcnt, bbase, bstore, offsets, csr_src);

    // Fused MFMA transform + attention scores
    gemm_mfma<<<(N_NODES + GBM - 1) / GBM, 256, 0, stream>>>(x, W, b, att, featb,
                                                             e_src, e_tar, e_self);

    // Single-pass atomic-free aggregation
    aggregate_k<<<(N_NODES + 3) / 4, 256, 0, stream>>>(offsets, csr_src, e_src, e_tar,
                                                       (const __hip_bfloat162*)featb,
                                                       e_self, out);
}

// Round 7
// 321.984 us; speedup vs baseline: 1.5877x; 1.5877x over previous
//
#include <hip/hip_runtime.h>
#include <hip/hip_bf16.h>
#include <math.h>

#define N_NODES 100000
#define N_EDGES 1600000
#define IN_CH 256
#define HC 128
#define NEG_SLOPE 0.2f

#define NB_C 196            // coarse buckets: tar>>9 (512 targets each)
#define CCAP 8704           // mean 8163, sigma~90 -> +6 sigma
#define CHUNK 6400          // 250 blocks * 6400 = 1.6M exactly

typedef __attribute__((ext_vector_type(8))) short short8;
typedef __attribute__((ext_vector_type(4))) float floatx4;

__device__ inline ushort f2b(float f) {
    __hip_bfloat16 h = __float2bfloat16(f);
    return *(ushort*)&h;
}

// ---------------------------------------------------------------------------
// Kernel 1: feat_bf16 = bf16(x @ W^T + b), fused attention scores.
// MFMA 16x16x32 bf16. Block = 256 thr (4 waves), BM=128 rows, full N=128.
// ---------------------------------------------------------------------------
#define GBM 128

__global__ __launch_bounds__(256, 2)
void gemm_mfma(const float* __restrict__ x, const float* __restrict__ W,
               const float* __restrict__ b, const float* __restrict__ att,
               __hip_bfloat16* __restrict__ featb,
               float* __restrict__ e_src, float* __restrict__ e_tar,
               float* __restrict__ e_self) {
    __shared__ ushort xs[128][72];
    __shared__ ushort wsh[128][72];

    const int tid  = threadIdx.x;
    const int wave = tid >> 6;
    const int lane = tid & 63;
    const int l16  = lane >> 4;
    const int lc   = lane & 15;
    const int row0 = blockIdx.x * GBM;

    floatx4 acc[2][8];
    #pragma unroll
    for (int mt = 0; mt < 2; ++mt)
        #pragma unroll
        for (int nt = 0; nt < 8; ++nt)
            acc[mt][nt] = (floatx4){0.f, 0.f, 0.f, 0.f};

    for (int kb = 0; kb < 4; ++kb) {           // K chunks of 64
        const int r  = tid >> 4;
        const int kq = tid & 15;
        #pragma unroll
        for (int i = 0; i < 8; ++i) {
            int rr = r + i * 16;
            int gr = row0 + rr;
            float4 v = make_float4(0.f, 0.f, 0.f, 0.f);
            if (gr < N_NODES)
                v = *(const float4*)&x[(size_t)gr * IN_CH + kb * 64 + kq * 4];
            ushort4 u;
            u.x = f2b(v.x); u.y = f2b(v.y); u.z = f2b(v.z); u.w = f2b(v.w);
            *(ushort4*)&xs[rr][kq * 4] = u;
        }
        #pragma unroll
        for (int i = 0; i < 8; ++i) {
            int rr = r + i * 16;
            float4 v = *(const float4*)&W[(size_t)rr * IN_CH + kb * 64 + kq * 4];
            ushort4 u;
            u.x = f2b(v.x); u.y = f2b(v.y); u.z = f2b(v.z); u.w = f2b(v.w);
            *(ushort4*)&wsh[rr][kq * 4] = u;
        }
        __syncthreads();
        #pragma unroll
        for (int ks = 0; ks < 2; ++ks) {
            short8 a0 = *(short8*)&xs[wave * 32 + lc][ks * 32 + l16 * 8];
            short8 a1 = *(short8*)&xs[wave * 32 + 16 + lc][ks * 32 + l16 * 8];
            short8 bf[8];
            #pragma unroll
            for (int nt = 0; nt < 8; ++nt)
                bf[nt] = *(short8*)&wsh[nt * 16 + lc][ks * 32 + l16 * 8];
            #pragma unroll
            for (int nt = 0; nt < 8; ++nt) {
                acc[0][nt] = __builtin_amdgcn_mfma_f32_16x16x32_bf16(a0, bf[nt], acc[0][nt], 0, 0, 0);
                acc[1][nt] = __builtin_amdgcn_mfma_f32_16x16x32_bf16(a1, bf[nt], acc[1][nt], 0, 0, 0);
            }
        }
        __syncthreads();
    }

    float av0[8], av1[8], bc[8];
    #pragma unroll
    for (int nt = 0; nt < 8; ++nt) {
        float2 av = *(const float2*)&att[(nt * 16 + lc) * 2];
        av0[nt] = av.x; av1[nt] = av.y;
        bc[nt] = b[nt * 16 + lc];
    }

    #pragma unroll
    for (int mt = 0; mt < 2; ++mt) {
        #pragma unroll
        for (int rg = 0; rg < 4; ++rg) {
            int row = row0 + wave * 32 + mt * 16 + l16 * 4 + rg;
            float s = 0.f, t = 0.f;
            float vals[8];
            #pragma unroll
            for (int nt = 0; nt < 8; ++nt) {
                float v = acc[mt][nt][rg] + bc[nt];
                vals[nt] = v;
                s += v * av0[nt];
                t += v * av1[nt];
            }
            #pragma unroll
            for (int off = 8; off; off >>= 1) {
                s += __shfl_xor(s, off);
                t += __shfl_xor(t, off);
            }
            if (row < N_NODES) {
                if (lc == 0) {
                    e_src[row] = s;
                    e_tar[row] = t;
                    float z = s + t;
                    float lr = z > 0.f ? z : NEG_SLOPE * z;
                    e_self[row] = __expf(lr);
                }
                #pragma unroll
                for (int nt = 0; nt < 8; ++nt)
                    featb[(size_t)row * HC + nt * 16 + lc] = __float2bfloat16(vals[nt]);
            }
        }
    }
}

// ---------------------------------------------------------------------------
// bin2_k: per-block run reservation. Each block histograms its 6400-edge
// chunk over 196 coarse buckets in LDS, reserves ONE contiguous run per
// bucket (one global atomic per non-empty bucket), then writes edges at
// block-private positions -> each ebuf cache line has a single writer block.
// Packed edge: src (17b) | local_tar (9b) << 17.
// ---------------------------------------------------------------------------
__global__ __launch_bounds__(256)
void bin2_k(const int* __restrict__ ei, int* __restrict__ gcur,
            int* __restrict__ ebuf) {
    __shared__ int lcnt[NB_C];
    __shared__ int lcur[NB_C];
    const int base = blockIdx.x * CHUNK;

    for (int i = threadIdx.x; i < NB_C; i += 256) lcnt[i] = 0;
    __syncthreads();

    for (int i = threadIdx.x; i < CHUNK; i += 256)
        atomicAdd(&lcnt[ei[base + i] >> 9], 1);
    __syncthreads();

    for (int bkt = threadIdx.x; bkt < NB_C; bkt += 256) {
        int c = lcnt[bkt];
        lcur[bkt] = c ? atomicAdd(&gcur[bkt], c) : 0;
    }
    __syncthreads();

    for (int i = threadIdx.x; i < CHUNK; i += 256) {
        int t = ei[base + i];
        int s = ei[N_EDGES + base + i];
        int bkt = t >> 9;
        int pos = atomicAdd(&lcur[bkt], 1);
        if (pos < CCAP)
            ebuf[bkt * CCAP + pos] = s | ((t & 511) << 17);
    }
}

// tiny exclusive scan over 196 bucket counts -> edge-space bases
__global__ void cscan_k(const int* __restrict__ gcur, int* __restrict__ nbase) {
    if (threadIdx.x == 0 && blockIdx.x == 0) {
        int run = 0;
        for (int i = 0; i < NB_C; ++i) {
            nbase[i] = run;
            int c = gcur[i]; if (c > CCAP) c = CCAP;
            run += c;
        }
        nbase[NB_C] = run;
    }
}

// ---------------------------------------------------------------------------
// bucket_csr2_k: one block per coarse bucket. LDS counting sort by local
// target (512 bins, Hillis-Steele scan), coalesced CSR + offsets write-out.
// ---------------------------------------------------------------------------
__global__ __launch_bounds__(256)
void bucket_csr2_k(const int* __restrict__ gcur, const int* __restrict__ nbase,
                   const int* __restrict__ ebuf, int* __restrict__ offsets,
                   int* __restrict__ csr_src) {
    const int b = blockIdx.x;
    int count = gcur[b]; if (count > CCAP) count = CCAP;
    const int base = nbase[b];
    const int tid = threadIdx.x;

    __shared__ int lcnt[512];
    __shared__ int lofs[512];
    __shared__ int lout[CCAP];

    lcnt[tid] = 0; lcnt[tid + 256] = 0;
    __syncthreads();

    const int* st = &ebuf[b * CCAP];
    for (int i = tid; i < count; i += 256)
        atomicAdd(&lcnt[st[i] >> 17], 1);
    __syncthreads();

    // inclusive Hillis-Steele scan over 512 bins (2 elems/thread)
    lofs[tid] = lcnt[tid]; lofs[tid + 256] = lcnt[tid + 256];
    __syncthreads();
    for (int off = 1; off < 512; off <<= 1) {
        int i0 = tid, i1 = tid + 256;
        int a0 = lofs[i0] + ((i0 >= off) ? lofs[i0 - off] : 0);
        int a1 = lofs[i1] + lofs[i1 - off];
        __syncthreads();
        lofs[i0] = a0; lofs[i1] = a1;
        __syncthreads();
    }
    // exclusive offsets -> lcnt (reused as scatter cursors)
    int e0 = lofs[tid] - lcnt[tid];
    int e1 = lofs[tid + 256] - lcnt[tid + 256];
    __syncthreads();
    lcnt[tid] = e0; lcnt[tid + 256] = e1;

    // write per-node global offsets BEFORE cursors are consumed
    int node0 = b * 512;
    {
        int n0 = node0 + tid, n1 = node0 + tid + 256;
        if (n0 < N_NODES) offsets[n0] = base + e0;
        if (n1 < N_NODES) offsets[n1] = base + e1;
    }
    if (b == NB_C - 1 && tid == 0) offsets[N_NODES] = base + count;
    __syncthreads();

    // LDS scatter by local target
    for (int i = tid; i < count; i += 256) {
        int v = st[i];
        int pos = atomicAdd(&lcnt[v >> 17], 1);
        lout[pos] = v & 0x1FFFF;
    }
    __syncthreads();

    // coalesced CSR write-out
    for (int i = tid; i < count; i += 256)
        csr_src[base + i] = lout[i];
}

// ---------------------------------------------------------------------------
// Aggregate: one wave per node, single pass, unnormalized accumulate.
// ---------------------------------------------------------------------------
__device__ inline float edge_e(float z) {
    float lr = z > 0.f ? z : NEG_SLOPE * z;
    return __expf(lr);
}

__global__ __launch_bounds__(256)
void aggregate_k(const int* __restrict__ offsets, const int* __restrict__ csr_src,
                 const float* __restrict__ e_src, const float* __restrict__ e_tar,
                 const __hip_bfloat162* __restrict__ featb,
                 const float* __restrict__ e_self, float* __restrict__ out) {
    int node = blockIdx.x * 4 + (threadIdx.x >> 6);
    if (node >= N_NODES) return;
    int lane = threadIdx.x & 63;
    int beg = offsets[node];
    int end = offsets[node + 1];
    float et = e_tar[node];
    float eself = e_self[node];

    float2 fs = __bfloat1622float2(featb[(size_t)node * 64 + lane]);
    float esum = eself;
    float accx = eself * fs.x, accy = eself * fs.y;

    int j = beg;
    for (; j + 3 < end; j += 4) {
        int s0 = csr_src[j];
        int s1 = csr_src[j + 1];
        int s2 = csr_src[j + 2];
        int s3 = csr_src[j + 3];
        float e0 = edge_e(e_src[s0] + et);
        float e1 = edge_e(e_src[s1] + et);
        float e2 = edge_e(e_src[s2] + et);
        float e3 = edge_e(e_src[s3] + et);
        float2 f0 = __bfloat1622float2(featb[(size_t)s0 * 64 + lane]);
        float2 f1 = __bfloat1622float2(featb[(size_t)s1 * 64 + lane]);
        float2 f2 = __bfloat1622float2(featb[(size_t)s2 * 64 + lane]);
        float2 f3 = __bfloat1622float2(featb[(size_t)s3 * 64 + lane]);
        esum += (e0 + e1) + (e2 + e3);
        accx += e0 * f0.x + e1 * f1.x + e2 * f2.x + e3 * f3.x;
        accy += e0 * f0.y + e1 * f1.y + e2 * f2.y + e3 * f3.y;
    }
    for (; j < end; ++j) {
        int s0 = csr_src[j];
        float e0 = edge_e(e_src[s0] + et);
        float2 f0 = __bfloat1622float2(featb[(size_t)s0 * 64 + lane]);
        esum += e0;
        accx += e0 * f0.x;
        accy += e0 * f0.y;
    }
    float inv = 1.f / esum;
    *(float2*)&out[(size_t)node * HC + lane * 2] = make_float2(accx * inv, accy * inv);
}

// ---------------------------------------------------------------------------
extern "C" void kernel_launch(void* const* d_in, const int* in_sizes, int n_in,
                              void* d_out, int out_size, void* d_ws, size_t ws_size,
                              hipStream_t stream) {
    const float* x   = (const float*)d_in[0];
    const int*   ei  = (const int*)d_in[1];     // [0:NE)=tar, [NE:2NE)=src
    const float* W   = (const float*)d_in[2];
    const float* b   = (const float*)d_in[3];
    const float* att = (const float*)d_in[4];
    float* out = (float*)d_out;

    __hip_bfloat16* featb = (__hip_bfloat16*)d_ws;            // 25.6 MB
    float* e_src   = (float*)(featb + (size_t)N_NODES * HC);
    float* e_tar   = e_src   + N_NODES;
    float* e_self  = e_tar   + N_NODES;
    int*   offsets = (int*)(e_self + N_NODES);                 // N+1
    int*   gcur    = offsets + N_NODES + 1;                    // NB_C
    int*   nbase   = gcur    + NB_C;                           // NB_C+1
    int*   csr_src = nbase   + NB_C + 1;                       // N_EDGES (6.4 MB)
    int*   ebuf    = csr_src + N_EDGES;                        // NB_C*CCAP (6.8 MB)

    (void)hipMemsetAsync(gcur, 0, NB_C * sizeof(int), stream);

    // topology build: run-reserved binning -> scan -> per-bucket LDS sort
    bin2_k<<<N_EDGES / CHUNK, 256, 0, stream>>>(ei, gcur, ebuf);
    cscan_k<<<1, 64, 0, stream>>>(gcur, nbase);
    bucket_csr2_k<<<NB_C, 256, 0, stream>>>(gcur, nbase, ebuf, offsets, csr_src);

    // fused MFMA transform + attention scores
    gemm_mfma<<<(N_NODES + GBM - 1) / GBM, 256, 0, stream>>>(x, W, b, att, featb,
                                                             e_src, e_tar, e_self);

    // single-pass atomic-free aggregation
    aggregate_k<<<(N_NODES + 3) / 4, 256, 0, stream>>>(offsets, csr_src, e_src, e_tar,
                                                       (const __hip_bfloat162*)featb,
                                                       e_self, out);
}